// Round 1
// baseline (201.279 us; speedup 1.0000x reference)
//
#include <hip/hip_runtime.h>
#include <hip/hip_bf16.h>

#define B_DIM 8192
#define D_DIM 2048
#define U_DIM 2048
#define KWORDS 64            // 2048 bits = 64 uint32 words per row/col
#define LDS_STRIDE 68        // 64 + 4 pad: breaks 4-way bank aliasing for b128 row reads

// ---------------- Kernel 1: pack input signs via wave ballot ----------------
// x: [B][D] fp32 -> xb: [B][D/64] u64. Lane i of each wave holds element d = base+i,
// so ballot bit i == sign bit of d = base+i. 2048 % 64 == 0 -> waves never cross rows.
__global__ void pack_x_kernel(const float* __restrict__ x,
                              unsigned long long* __restrict__ xb) {
    int idx = blockIdx.x * blockDim.x + threadIdx.x;   // one element per thread
    float v = x[idx];
    unsigned long long m = __ballot(v >= 0.0f);
    if ((threadIdx.x & 63) == 0) xb[idx >> 6] = m;
}

// ---------------- Kernel 2: pack kernel signs (transposed) ----------------
// k: [D][U] fp32 -> kb: [U][D/64] u64 (bits run along D for a fixed unit j).
// 64x64 tile through LDS so global reads stay coalesced.
__global__ void pack_k_kernel(const float* __restrict__ k,
                              unsigned long long* __restrict__ kb) {
    __shared__ float tile[64][65];                     // +1 pad: stride-65 -> conflict-free column reads
    const int j0 = (blockIdx.x & 31) * 64;             // 2048/64 = 32 col tiles
    const int d0 = (blockIdx.x >> 5) * 64;             // 32 row tiles
    const int tid  = threadIdx.x;
    const int lane = tid & 63;
    const int wv   = tid >> 6;                         // 4 waves

    // coalesced load: 64 lanes read 64 consecutive floats of one row
    for (int i = 0; i < 16; i++) {
        int row = i * 4 + wv;
        tile[row][lane] = k[(size_t)(d0 + row) * U_DIM + j0 + lane];
    }
    __syncthreads();

    // each wave packs 16 columns: lane i supplies bit for d = d0 + i
    for (int c = wv * 16; c < wv * 16 + 16; c++) {
        float v = tile[lane][c];
        unsigned long long m = __ballot(v >= 0.0f);
        if (lane == 0) kb[(size_t)(j0 + c) * (D_DIM / 64) + (d0 >> 6)] = m;
    }
}

// ---------------- Kernel 3: binary GEMM via xor + popcount ----------------
// out[i][j] = D - 2*popc(xbits[i] ^ kbits[j]) + bias[j]
// 64x64 output tile per block, 256 threads, 4x4 outputs/thread.
__launch_bounds__(256)
__global__ void bgemm_kernel(const unsigned int* __restrict__ xb,   // [B][64]
                             const unsigned int* __restrict__ kb,   // [U][64]
                             const float* __restrict__ bias,
                             float* __restrict__ out) {
    __shared__ unsigned int xs[64 * LDS_STRIDE];
    __shared__ unsigned int ks[64 * LDS_STRIDE];

    const int bx  = blockIdx.x;   // col tile (32)
    const int by  = blockIdx.y;   // row tile (128)
    const int tid = threadIdx.x;

    // Both bit tiles are contiguous 16KB chunks -> fully coalesced uint4 loads.
    const uint4* xsrc = (const uint4*)(xb + (size_t)(by * 64) * KWORDS);
    const uint4* ksrc = (const uint4*)(kb + (size_t)(bx * 64) * KWORDS);
#pragma unroll
    for (int i = 0; i < 4; i++) {
        int flat = tid + i * 256;          // uint4 index 0..1023
        int r    = flat >> 4;              // 16 uint4 per 64-word row
        int w4   = flat & 15;
        uint4 xv = xsrc[flat];
        uint4 kv = ksrc[flat];
        *((uint4*)&xs[r * LDS_STRIDE + w4 * 4]) = xv;
        *((uint4*)&ks[r * LDS_STRIDE + w4 * 4]) = kv;
    }
    __syncthreads();

    const int tr = (tid >> 4) * 4;         // thread's 4 rows
    const int tc = (tid & 15) * 4;         // thread's 4 cols
    int acc[4][4] = {};

    for (int w = 0; w < KWORDS; w += 4) {
        uint4 xv[4], kv[4];
#pragma unroll
        for (int r = 0; r < 4; r++) xv[r] = *((const uint4*)&xs[(tr + r) * LDS_STRIDE + w]);
#pragma unroll
        for (int c = 0; c < 4; c++) kv[c] = *((const uint4*)&ks[(tc + c) * LDS_STRIDE + w]);
#pragma unroll
        for (int r = 0; r < 4; r++)
#pragma unroll
            for (int c = 0; c < 4; c++) {
                acc[r][c] += __popc(xv[r].x ^ kv[c].x);
                acc[r][c] += __popc(xv[r].y ^ kv[c].y);
                acc[r][c] += __popc(xv[r].z ^ kv[c].z);
                acc[r][c] += __popc(xv[r].w ^ kv[c].w);
            }
    }

    const int row0 = by * 64 + tr;
    const int col0 = bx * 64 + tc;
    const float b0 = bias[col0 + 0], b1 = bias[col0 + 1],
                b2 = bias[col0 + 2], b3 = bias[col0 + 3];
#pragma unroll
    for (int r = 0; r < 4; r++) {
        float4 o;
        o.x = (float)(D_DIM - 2 * acc[r][0]) + b0;
        o.y = (float)(D_DIM - 2 * acc[r][1]) + b1;
        o.z = (float)(D_DIM - 2 * acc[r][2]) + b2;
        o.w = (float)(D_DIM - 2 * acc[r][3]) + b3;
        *((float4*)&out[(size_t)(row0 + r) * U_DIM + col0]) = o;
    }
}

extern "C" void kernel_launch(void* const* d_in, const int* in_sizes, int n_in,
                              void* d_out, int out_size, void* d_ws, size_t ws_size,
                              hipStream_t stream) {
    const float* x    = (const float*)d_in[0];   // [8192][2048]
    const float* k    = (const float*)d_in[1];   // [2048][2048]
    const float* bias = (const float*)d_in[2];   // [2048]
    float* out = (float*)d_out;

    unsigned long long* xbits = (unsigned long long*)d_ws;                       // 2 MB
    unsigned long long* kbits = (unsigned long long*)((char*)d_ws + (size_t)B_DIM * (D_DIM / 8)); // 0.5 MB

    // pack x: one thread per element
    pack_x_kernel<<<(B_DIM * D_DIM) / 256, 256, 0, stream>>>(x, xbits);
    // pack k: 32x32 tiles of 64x64
    pack_k_kernel<<<32 * 32, 256, 0, stream>>>(k, kbits);
    // bit-GEMM: 32 col tiles x 128 row tiles
    dim3 grid(U_DIM / 64, B_DIM / 64);
    bgemm_kernel<<<grid, 256, 0, stream>>>((const unsigned int*)xbits,
                                           (const unsigned int*)kbits, bias, out);
}